// Round 4
// baseline (997.897 us; speedup 1.0000x reference)
//
#include <hip/hip_runtime.h>
#include <hip/hip_bf16.h>
#include <cstdint>
#include <cstddef>

typedef unsigned short u16;
typedef u16 u16x8 __attribute__((ext_vector_type(8)));
typedef u16 u16x4 __attribute__((ext_vector_type(4)));
typedef __bf16 bf16x8 __attribute__((ext_vector_type(8)));
typedef float f32x4 __attribute__((ext_vector_type(4)));

// 12-lead ECG adjacency (with self loops) as bitmasks; degree = popcount.
__device__ const unsigned short ADJ_MASK[12] = {
    95u, 575u, 2095u, 15u, 19u, 38u, 193u, 448u, 896u, 1794u, 3584u, 3076u};

__device__ __forceinline__ float b2f(u16 u) {
  union { unsigned int i; float f; } v;
  v.i = ((unsigned int)u) << 16;
  return v.f;
}
__device__ __forceinline__ u16 f2b(float f) {
  union { float f; unsigned int i; } v;
  v.f = f;
  unsigned int r = v.i + 0x7fffu + ((v.i >> 16) & 1u);
  return (u16)(r >> 16);
}

__device__ __forceinline__ void build_anorm(float* An) {
  int t = threadIdx.x;
  if (t < 144) {
    int i = t / 12, j = t % 12;
    float di = (float)__popc((int)ADJ_MASK[i]);
    float dj = (float)__popc((int)ADJ_MASK[j]);
    An[t] = ((ADJ_MASK[i] >> j) & 1) ? (1.0f / sqrtf(di * dj)) : 0.0f;
  }
}

// -------- runtime dtype detector: is this buffer fp32 (1) or bf16 (0)? ------
// Samples 4096 u32 words; counts low-half u16s whose bf16 exponent is
// implausible for N(0,sigma) data. fp32 mantissa halves ~81% implausible.
__global__ void __launch_bounds__(256) k_detect(const void* p, int* flag) {
  const unsigned int* w = (const unsigned int*)p;
  __shared__ int s;
  if (threadIdx.x == 0) s = 0;
  __syncthreads();
  int cnt = 0;
  for (int t = 0; t < 16; ++t) {
    unsigned int v = w[t * 256 + threadIdx.x];
    unsigned int e = (v >> 7) & 0xFFu;  // low-half bf16 exponent
    if (e != 0u && (e < 0x5Au || e > 0x89u)) ++cnt;
  }
  atomicAdd(&s, cnt);
  __syncthreads();
  if (threadIdx.x == 0) *flag = (s > 1024) ? 1 : 0;
}

// -------- flag-aware element convert to bf16 ---------------------------------
__global__ void k_cvt(const void* in, u16* out, int n, const int* flag) {
  int idx = blockIdx.x * 256 + threadIdx.x;
  if (idx < n) {
    out[idx] = (*flag) ? f2b(((const float*)in)[idx]) : ((const u16*)in)[idx];
  }
}

// -------- flag-aware transpose+convert: in [R][C] -> out [C][R] bf16 ---------
__global__ void k_transpose_cvt(const void* in, u16* out, int R, int C,
                                const int* flag) {
  long idx = (long)blockIdx.x * 256 + threadIdx.x;
  if (idx < (long)R * C) {
    long c = idx / R, r = idx - c * R;
    u16 v = (*flag) ? f2b(((const float*)in)[r * C + c])
                    : ((const u16*)in)[r * C + c];
    out[c * R + r] = v;
  }
}

// ---- lead-mix (+bias,+relu): out[b,i,f] = relu(b[f] + sum_j An[i][j] G[b,j,f])
__global__ void __launch_bounds__(256) k_mix(const u16* __restrict__ in,
                                             const u16* __restrict__ bias,
                                             u16* __restrict__ out, int relu) {
  __shared__ u16 X[6144];
  __shared__ float An[144];
  build_anorm(An);
  const int tid = threadIdx.x;
  const long base = (long)blockIdx.x * 6144;
#pragma unroll
  for (int i = 0; i < 3; ++i) {
    int idx = i * 256 + tid;
    *(u16x8*)(X + idx * 8) = *(const u16x8*)(in + base + idx * 8);
  }
  __syncthreads();
#pragma unroll
  for (int v = 0; v < 3; ++v) {
    int idx = v * 256 + tid;
    int s = idx / 384;
    int rem = idx - s * 384;
    int i = rem >> 5;
    int fg = rem & 31;
    float a[8];
#pragma unroll
    for (int u = 0; u < 8; ++u) a[u] = b2f(bias[fg * 8 + u]);
    for (int j = 0; j < 12; ++j) {
      float c = An[i * 12 + j];
      if (c != 0.0f) {
        u16x8 y = *(const u16x8*)(X + (s * 12 + j) * 256 + fg * 8);
#pragma unroll
        for (int u = 0; u < 8; ++u) a[u] += c * b2f(y[u]);
      }
    }
    u16x8 o;
#pragma unroll
    for (int u = 0; u < 8; ++u) {
      float vv = relu ? fmaxf(a[u], 0.0f) : a[u];
      o[u] = f2b(vv);
    }
    *(u16x8*)(out + base + idx * 8) = o;
  }
}

// ---------------- MFMA GEMM core: C[96,256] = A[96,K](lda) * Bt[256,K]^T -----
// A may be fp32 (isf32=1) or bf16; Bt always bf16.
__device__ __forceinline__ void gemm_core(const void* __restrict__ A, int lda,
                                          int isf32,
                                          const u16* __restrict__ Bt,
                                          u16* As, u16* Bs,
                                          long m0, long n0, int K,
                                          f32x4 acc[6][4]) {
  const int tid = threadIdx.x;
  const int wave = tid >> 6, lane = tid & 63;
  const int q = lane >> 4, r16 = lane & 15;
  f32x4 zero = {0.f, 0.f, 0.f, 0.f};
#pragma unroll
  for (int a = 0; a < 6; ++a)
#pragma unroll
    for (int b = 0; b < 4; ++b) acc[a][b] = zero;

  for (int k0 = 0; k0 < K; k0 += 64) {
    if (isf32) {
      const float* Af = (const float*)A;
#pragma unroll
      for (int i = 0; i < 3; ++i) {  // stage A: 96x64 with convert
        int idx = i * 256 + tid;
        int rr = idx >> 3, cg = idx & 7;
        const float* sp = Af + (m0 + rr) * (long)lda + k0 + cg * 8;
        u16x8 t;
#pragma unroll
        for (int u = 0; u < 8; ++u) t[u] = f2b(sp[u]);
        *(u16x8*)(As + rr * 72 + cg * 8) = t;
      }
    } else {
      const u16* Ab = (const u16*)A;
#pragma unroll
      for (int i = 0; i < 3; ++i) {  // stage A: 96x64
        int idx = i * 256 + tid;
        int rr = idx >> 3, cg = idx & 7;
        *(u16x8*)(As + rr * 72 + cg * 8) =
            *(const u16x8*)(Ab + (m0 + rr) * (long)lda + k0 + cg * 8);
      }
    }
#pragma unroll
    for (int i = 0; i < 8; ++i) {  // stage Bt: 256x64
      int idx = i * 256 + tid;
      int rr = idx >> 3, cg = idx & 7;
      *(u16x8*)(Bs + rr * 72 + cg * 8) =
          *(const u16x8*)(Bt + (n0 + rr) * (long)K + k0 + cg * 8);
    }
    __syncthreads();
#pragma unroll
    for (int ks = 0; ks < 64; ks += 32) {
      bf16x8 af[6], bfv[4];
#pragma unroll
      for (int rb = 0; rb < 6; ++rb)
        af[rb] = *(const bf16x8*)(As + (rb * 16 + r16) * 72 + ks + q * 8);
#pragma unroll
      for (int cb = 0; cb < 4; ++cb)
        bfv[cb] = *(const bf16x8*)(Bs + ((wave * 4 + cb) * 16 + r16) * 72 + ks + q * 8);
#pragma unroll
      for (int rb = 0; rb < 6; ++rb)
#pragma unroll
        for (int cb = 0; cb < 4; ++cb)
          acc[rb][cb] = __builtin_amdgcn_mfma_f32_16x16x32_bf16(
              af[rb], bfv[cb], acc[rb][cb], 0, 0, 0);
    }
    __syncthreads();
  }
}

// ---------------- generic GEMM (no bias), bf16 out ---------------------------
// In-place safe (C may alias A). aflag: nullptr => A is bf16.
__global__ void __launch_bounds__(256) k_gemm(const void* __restrict__ A, int lda,
                                              const u16* __restrict__ Bt,
                                              u16* __restrict__ C,
                                              int K, int Ntot,
                                              const int* aflag) {
  __shared__ u16 As[96 * 72];
  __shared__ u16 Bs[256 * 72];
  f32x4 acc[6][4];
  const long m0 = (long)blockIdx.x * 96;
  const long n0 = (long)blockIdx.y * 256;
  int isf32 = aflag ? *aflag : 0;
  gemm_core(A, lda, isf32, Bt, As, Bs, m0, n0, K, acc);
  const int tid = threadIdx.x;
  const int wave = tid >> 6, lane = tid & 63;
  const int q = lane >> 4, r16 = lane & 15;
#pragma unroll
  for (int cb = 0; cb < 4; ++cb) {
    long col = n0 + (wave * 4 + cb) * 16 + r16;
#pragma unroll
    for (int rb = 0; rb < 6; ++rb) {
#pragma unroll
      for (int rr = 0; rr < 4; ++rr) {
        long row = m0 + rb * 16 + q * 4 + rr;
        C[row * (long)Ntot + col] = f2b(acc[rb][cb][rr]);
      }
    }
  }
}

// ------- fused QKV + attention + out-proj + residual + LN + lead-mix ---------
// 2 samples per block (24 rows, padded to M=32). All weights are bf16 ws copies.
__global__ void __launch_bounds__(256) k_attn_mega(
    u16* __restrict__ H, const u16* __restrict__ inw,
    const u16* __restrict__ inb, const u16* __restrict__ outw,
    const u16* __restrict__ outb, const u16* __restrict__ lng,
    const u16* __restrict__ lnb) {
  __shared__ u16 Hs[32 * 264];   // H2 tile (+pad rows zeroed), later pre-LN x
  __shared__ u16 Qs[32 * 264];   // Q, later attention output O
  __shared__ u16 KVs[24 * 512];  // K | V
  __shared__ float Sc[4][2][12][12];
  __shared__ float An[144];
  __shared__ float mu[24], rs[24];
  const int tid = threadIdx.x;
  const int wave = tid >> 6, lane = tid & 63;
  const int q = lane >> 4, r16 = lane & 15;
  build_anorm(An);
  const long base = (long)blockIdx.x * 6144;  // 24*256
#pragma unroll
  for (int i = 0; i < 3; ++i) {
    int idx = i * 256 + tid;
    int rr = idx >> 5, cg = idx & 31;
    *(u16x8*)(Hs + rr * 264 + cg * 8) = *(const u16x8*)(H + base + idx * 8);
  }
  {
    int rr = 24 + (tid >> 5), cg = tid & 31;
    u16x8 z = {0, 0, 0, 0, 0, 0, 0, 0};
    *(u16x8*)(Hs + rr * 264 + cg * 8) = z;
  }
  __syncthreads();
  // (b) QKV GEMM: [32,256] @ inw[768,256]^T
  {
    f32x4 acc[2][12];
    f32x4 zero = {0.f, 0.f, 0.f, 0.f};
#pragma unroll
    for (int rb = 0; rb < 2; ++rb)
#pragma unroll
      for (int c = 0; c < 12; ++c) acc[rb][c] = zero;
    for (int k0 = 0; k0 < 256; k0 += 32) {
      bf16x8 af[2];
#pragma unroll
      for (int rb = 0; rb < 2; ++rb)
        af[rb] = *(const bf16x8*)(Hs + (rb * 16 + r16) * 264 + k0 + q * 8);
#pragma unroll
      for (int c = 0; c < 12; ++c) {
        bf16x8 bf = *(const bf16x8*)(inw + (long)((wave * 12 + c) * 16 + r16) * 256 + k0 + q * 8);
#pragma unroll
        for (int rb = 0; rb < 2; ++rb)
          acc[rb][c] = __builtin_amdgcn_mfma_f32_16x16x32_bf16(af[rb], bf, acc[rb][c], 0, 0, 0);
      }
    }
#pragma unroll
    for (int c = 0; c < 12; ++c) {
      int col = (wave * 12 + c) * 16 + r16;
      float bv = b2f(inb[col]);
#pragma unroll
      for (int rb = 0; rb < 2; ++rb)
#pragma unroll
        for (int rr2 = 0; rr2 < 4; ++rr2) {
          int row = rb * 16 + q * 4 + rr2;
          float v = acc[rb][c][rr2] + bv;
          if (col < 256) Qs[row * 264 + col] = f2b(v);
          else if (row < 24) KVs[row * 512 + col - 256] = f2b(v);
        }
    }
  }
  __syncthreads();
  // (c) scores
  {
    int h = wave;
#pragma unroll
    for (int t = 0; t < 5; ++t) {
      int p = t * 64 + lane;
      if (p < 288) {
        int s = p / 144, r = p - s * 144, i = r / 12, j = r - i * 12;
        const u16* qp = Qs + (s * 12 + i) * 264 + h * 64;
        const u16* kp = KVs + (s * 12 + j) * 512 + h * 64;
        float dot = 0.f;
#pragma unroll
        for (int dv = 0; dv < 8; ++dv) {
          u16x8 qv = *(const u16x8*)(qp + dv * 8);
          u16x8 kv = *(const u16x8*)(kp + dv * 8);
#pragma unroll
          for (int u = 0; u < 8; ++u) dot += b2f(qv[u]) * b2f(kv[u]);
        }
        Sc[h][s][i][j] = dot * 0.125f;
      }
    }
  }
  __syncthreads();
  if (lane < 24) {
    int h = wave, s = lane / 12, i = lane - (lane / 12) * 12;
    float m = -1e30f;
#pragma unroll
    for (int j = 0; j < 12; ++j) m = fmaxf(m, Sc[h][s][i][j]);
    float e[12];
    float ssum = 0.f;
#pragma unroll
    for (int j = 0; j < 12; ++j) {
      e[j] = __expf(Sc[h][s][i][j] - m);
      ssum += e[j];
    }
    float inv = 1.0f / ssum;
#pragma unroll
    for (int j = 0; j < 12; ++j) Sc[h][s][i][j] = e[j] * inv;
  }
  __syncthreads();
  // (d) O = attn @ V  -> overwrite Q slots
  {
    int h = wave, d = lane;
    for (int si = 0; si < 24; ++si) {
      int s = si / 12;
      float o = 0.f;
#pragma unroll
      for (int j = 0; j < 12; ++j)
        o += Sc[h][s][si - s * 12][j] * b2f(KVs[(s * 12 + j) * 512 + 256 + h * 64 + d]);
      Qs[si * 264 + h * 64 + d] = f2b(o);
    }
  }
  __syncthreads();
  // (e) out-proj + bias + residual -> pre-LN x in place of Hs
  {
    f32x4 acc[2][4];
    f32x4 zero = {0.f, 0.f, 0.f, 0.f};
#pragma unroll
    for (int rb = 0; rb < 2; ++rb)
#pragma unroll
      for (int cb = 0; cb < 4; ++cb) acc[rb][cb] = zero;
    for (int k0 = 0; k0 < 256; k0 += 32) {
      bf16x8 af[2];
#pragma unroll
      for (int rb = 0; rb < 2; ++rb)
        af[rb] = *(const bf16x8*)(Qs + (rb * 16 + r16) * 264 + k0 + q * 8);
#pragma unroll
      for (int cb = 0; cb < 4; ++cb) {
        bf16x8 bf = *(const bf16x8*)(outw + (long)((wave * 4 + cb) * 16 + r16) * 256 + k0 + q * 8);
#pragma unroll
        for (int rb = 0; rb < 2; ++rb)
          acc[rb][cb] = __builtin_amdgcn_mfma_f32_16x16x32_bf16(af[rb], bf, acc[rb][cb], 0, 0, 0);
      }
    }
#pragma unroll
    for (int cb = 0; cb < 4; ++cb) {
      int col = (wave * 4 + cb) * 16 + r16;
      float ob = b2f(outb[col]);
#pragma unroll
      for (int rb = 0; rb < 2; ++rb)
#pragma unroll
        for (int rr2 = 0; rr2 < 4; ++rr2) {
          int row = rb * 16 + q * 4 + rr2;
          if (row < 24) {
            float x = acc[rb][cb][rr2] + ob + b2f(Hs[row * 264 + col]);
            Hs[row * 264 + col] = f2b(x);
          }
        }
    }
  }
  __syncthreads();
  // (f) LN stats per row
  {
    for (int rr2 = wave * 6; rr2 < wave * 6 + 6; ++rr2) {
      float s1 = 0.f, s2 = 0.f;
#pragma unroll
      for (int u = 0; u < 4; ++u) {
        float xv = b2f(Hs[rr2 * 264 + u * 64 + lane]);
        s1 += xv;
        s2 += xv * xv;
      }
#pragma unroll
      for (int off = 32; off > 0; off >>= 1) {
        s1 += __shfl_down(s1, off, 64);
        s2 += __shfl_down(s2, off, 64);
      }
      if (lane == 0) {
        float m = s1 * (1.0f / 256.0f);
        mu[rr2] = m;
        rs[rr2] = rsqrtf(s2 * (1.0f / 256.0f) - m * m + 1e-5f);
      }
    }
  }
  __syncthreads();
  // (g) LN apply + lead-mix + global write
  {
    float gvv = b2f(lng[tid]);
    float bvv = b2f(lnb[tid]);
#pragma unroll
    for (int s = 0; s < 2; ++s) {
      float xn[12];
#pragma unroll
      for (int j = 0; j < 12; ++j) {
        int row = s * 12 + j;
        xn[j] = (b2f(Hs[row * 264 + tid]) - mu[row]) * rs[row] * gvv + bvv;
      }
#pragma unroll
      for (int i = 0; i < 12; ++i) {
        float o = 0.f;
#pragma unroll
        for (int j = 0; j < 12; ++j) o += An[i * 12 + j] * xn[j];
        H[base + (s * 12 + i) * 256 + tid] = f2b(o);
      }
    }
  }
}

// ---------- final GEMM + bias + attention-pooling; OUTPUT = float32 ----------
__global__ void __launch_bounds__(256) k_gemm_pool(const u16* __restrict__ A,
                                                   const u16* __restrict__ Bt,
                                                   const u16* __restrict__ bias,
                                                   float* __restrict__ out) {
  __shared__ __align__(16) char smraw[50688];
  __shared__ float rowsum[96];
  __shared__ float wsm[96];
  u16* As = (u16*)smraw;
  u16* Bs = As + 96 * 72;
  u16* Y = (u16*)smraw;
  f32x4 acc[6][4];
  const long m0 = (long)blockIdx.x * 96;
  gemm_core(A, 256, 0, Bt, As, Bs, m0, 0, 256, acc);
  const int tid = threadIdx.x;
  const int wave = tid >> 6, lane = tid & 63;
  const int q = lane >> 4, r16 = lane & 15;
#pragma unroll
  for (int cb = 0; cb < 4; ++cb) {
    int col = (wave * 4 + cb) * 16 + r16;
    float bvv = b2f(bias[col]);
#pragma unroll
    for (int rb = 0; rb < 6; ++rb)
#pragma unroll
      for (int rr = 0; rr < 4; ++rr) {
        int row = rb * 16 + q * 4 + rr;
        Y[row * 264 + col] = f2b(acc[rb][cb][rr] + bvv);
      }
  }
  __syncthreads();
  for (int row = wave; row < 96; row += 4) {
    float s = 0.f;
#pragma unroll
    for (int u = 0; u < 4; ++u) s += b2f(Y[row * 264 + u * 64 + lane]);
#pragma unroll
    for (int off = 32; off > 0; off >>= 1) s += __shfl_down(s, off, 64);
    if (lane == 0) rowsum[row] = s;
  }
  __syncthreads();
  if (tid < 8) {
    float m = -1e30f;
#pragma unroll
    for (int l = 0; l < 12; ++l) m = fmaxf(m, rowsum[tid * 12 + l]);
    float e[12];
    float ssum = 0.f;
#pragma unroll
    for (int l = 0; l < 12; ++l) {
      e[l] = __expf((rowsum[tid * 12 + l] - m) * (1.0f / 256.0f));
      ssum += e[l];
    }
    float inv = 1.0f / ssum;
#pragma unroll
    for (int l = 0; l < 12; ++l) wsm[tid * 12 + l] = e[l] * inv;
  }
  __syncthreads();
  {
    int s = tid >> 5, cg = tid & 31;
    float wa[8], mx[8];
#pragma unroll
    for (int u = 0; u < 8; ++u) {
      wa[u] = 0.f;
      mx[u] = -1e30f;
    }
#pragma unroll
    for (int l = 0; l < 12; ++l) {
      float w = wsm[s * 12 + l];
      u16x8 yv = *(const u16x8*)(Y + (s * 12 + l) * 264 + cg * 8);
#pragma unroll
      for (int u = 0; u < 8; ++u) {
        float y = b2f(yv[u]);
        wa[u] += w * y;
        mx[u] = fmaxf(mx[u], y);
      }
    }
    long ob = ((long)blockIdx.x * 8 + s) * 512;
#pragma unroll
    for (int u = 0; u < 8; ++u) {
      out[ob + cg * 8 + u] = wa[u];
      out[ob + 256 + cg * 8 + u] = mx[u];
    }
  }
}

extern "C" void kernel_launch(void* const* d_in, const int* in_sizes, int n_in,
                              void* d_out, int out_size, void* d_ws,
                              size_t ws_size, hipStream_t stream) {
  (void)in_sizes; (void)n_in; (void)out_size; (void)ws_size;
  const void* x    = d_in[0];
  const void* W1   = d_in[1];
  const void* b1   = d_in[2];
  const void* W2   = d_in[3];
  const void* b2   = d_in[4];
  const void* W3   = d_in[5];
  const void* b3   = d_in[6];
  const void* inw  = d_in[7];
  const void* inb  = d_in[8];
  const void* outw = d_in[9];
  const void* outb = d_in[10];
  const void* lng  = d_in[11];
  const void* lnb  = d_in[12];
  float* out = (float*)d_out;

  // ws layout (u16 offsets); total ~49.1 MiB
  u16* ws16 = (u16*)d_ws;
  int* flagX = (int*)d_ws;            // byte 0
  int* flagW = (int*)d_ws + 1;        // byte 4
  u16* W1T   = ws16 + 64;
  u16* W2T   = W1T + 131072;
  u16* W3T   = W2T + 65536;
  u16* inw_b = W3T + 65536;
  u16* outw_b = inw_b + 196608;
  u16* b1b   = outw_b + 65536;
  u16* b2b   = b1b + 256;
  u16* b3b   = b2b + 256;
  u16* inbb  = b3b + 256;
  u16* outbb = inbb + 768;
  u16* lngb  = outbb + 256;
  u16* lnbb  = lngb + 256;
  u16* BUF   = lnbb + 256;            // 25165824 elems

  k_detect<<<1, 256, 0, stream>>>(x, flagX);
  k_detect<<<1, 256, 0, stream>>>(W1, flagW);

  k_cvt<<<1, 256, 0, stream>>>(b1, b1b, 256, flagW);
  k_cvt<<<1, 256, 0, stream>>>(b2, b2b, 256, flagW);
  k_cvt<<<1, 256, 0, stream>>>(b3, b3b, 256, flagW);
  k_cvt<<<3, 256, 0, stream>>>(inb, inbb, 768, flagW);
  k_cvt<<<1, 256, 0, stream>>>(outb, outbb, 256, flagW);
  k_cvt<<<1, 256, 0, stream>>>(lng, lngb, 256, flagW);
  k_cvt<<<1, 256, 0, stream>>>(lnb, lnbb, 256, flagW);
  k_cvt<<<768, 256, 0, stream>>>(inw, inw_b, 196608, flagW);
  k_cvt<<<256, 256, 0, stream>>>(outw, outw_b, 65536, flagW);
  k_transpose_cvt<<<512, 256, 0, stream>>>(W1, W1T, 512, 256, flagW);
  k_transpose_cvt<<<256, 256, 0, stream>>>(W2, W2T, 256, 256, flagW);
  k_transpose_cvt<<<256, 256, 0, stream>>>(W3, W3T, 256, 256, flagW);

  // G1 = x@W1 (A-mix commutes with the feature matmul)
  k_gemm<<<dim3(1024, 1), 256, 0, stream>>>(x, 512, W1T, BUF, 512, 256, flagX);
  // H1 = relu(A.G1 + b1), in place
  k_mix<<<4096, 256, 0, stream>>>(BUF, b1b, BUF, 1);
  // G2 = H1@W2, in place
  k_gemm<<<dim3(1024, 1), 256, 0, stream>>>(BUF, 256, W2T, BUF, 256, 256, nullptr);
  // H2 = relu(A.G2 + b2), in place
  k_mix<<<4096, 256, 0, stream>>>(BUF, b2b, BUF, 1);
  // HL = A.( LN(H2 + MHA(H2)) ), fused, in place
  k_attn_mega<<<4096, 256, 0, stream>>>(BUF, inw_b, inbb, outw_b, outbb, lngb, lnbb);
  // out = pool( HL@W3 + b3 )  -- float32 output
  k_gemm_pool<<<1024, 256, 0, stream>>>(BUF, W3T, b3b, out);
}

// Round 5
// 668.537 us; speedup vs baseline: 1.4927x; 1.4927x over previous
//
#include <hip/hip_runtime.h>
#include <hip/hip_bf16.h>
#include <cstdint>
#include <cstddef>

typedef unsigned short u16;
typedef u16 u16x8 __attribute__((ext_vector_type(8)));
typedef u16 u16x4 __attribute__((ext_vector_type(4)));
typedef __bf16 bf16x8 __attribute__((ext_vector_type(8)));
typedef float f32x4 __attribute__((ext_vector_type(4)));

__device__ const unsigned short ADJ_MASK[12] = {
    95u, 575u, 2095u, 15u, 19u, 38u, 193u, 448u, 896u, 1794u, 3584u, 3076u};

__device__ __forceinline__ float b2f(u16 u) {
  union { unsigned int i; float f; } v;
  v.i = ((unsigned int)u) << 16;
  return v.f;
}
__device__ __forceinline__ u16 f2b(float f) {
  union { float f; unsigned int i; } v;
  v.f = f;
  unsigned int r = v.i + 0x7fffu + ((v.i >> 16) & 1u);
  return (u16)(r >> 16);
}

__device__ __forceinline__ void build_anorm(float* An) {
  int t = threadIdx.x;
  if (t < 144) {
    int i = t / 12, j = t % 12;
    float di = (float)__popc((int)ADJ_MASK[i]);
    float dj = (float)__popc((int)ADJ_MASK[j]);
    An[t] = ((ADJ_MASK[i] >> j) & 1) ? (1.0f / sqrtf(di * dj)) : 0.0f;
  }
}

// -------- runtime dtype detector: is this buffer fp32 (1) or bf16 (0)? ------
__global__ void __launch_bounds__(256) k_detect(const void* p, int* flag) {
  const unsigned int* w = (const unsigned int*)p;
  __shared__ int s;
  if (threadIdx.x == 0) s = 0;
  __syncthreads();
  int cnt = 0;
  for (int t = 0; t < 16; ++t) {
    unsigned int v = w[t * 256 + threadIdx.x];
    unsigned int e = (v >> 7) & 0xFFu;
    if (e != 0u && (e < 0x5Au || e > 0x89u)) ++cnt;
  }
  atomicAdd(&s, cnt);
  __syncthreads();
  if (threadIdx.x == 0) *flag = (s > 1024) ? 1 : 0;
}

__global__ void k_cvt(const void* in, u16* out, int n, const int* flag) {
  int idx = blockIdx.x * 256 + threadIdx.x;
  if (idx < n) {
    out[idx] = (*flag) ? f2b(((const float*)in)[idx]) : ((const u16*)in)[idx];
  }
}

__global__ void k_transpose_cvt(const void* in, u16* out, int R, int C,
                                const int* flag) {
  long idx = (long)blockIdx.x * 256 + threadIdx.x;
  if (idx < (long)R * C) {
    long c = idx / R, r = idx - c * R;
    u16 v = (*flag) ? f2b(((const float*)in)[r * C + c])
                    : ((const u16*)in)[r * C + c];
    out[c * R + r] = v;
  }
}

// ---- lead-mix (+bias,+relu) ------------------------------------------------
__global__ void __launch_bounds__(256) k_mix(const u16* __restrict__ in,
                                             const u16* __restrict__ bias,
                                             u16* __restrict__ out, int relu) {
  __shared__ u16 X[6144];
  __shared__ float An[144];
  build_anorm(An);
  const int tid = threadIdx.x;
  const long base = (long)blockIdx.x * 6144;
#pragma unroll
  for (int i = 0; i < 3; ++i) {
    int idx = i * 256 + tid;
    *(u16x8*)(X + idx * 8) = *(const u16x8*)(in + base + idx * 8);
  }
  __syncthreads();
#pragma unroll
  for (int v = 0; v < 3; ++v) {
    int idx = v * 256 + tid;
    int s = idx / 384;
    int rem = idx - s * 384;
    int i = rem >> 5;
    int fg = rem & 31;
    float a[8];
#pragma unroll
    for (int u = 0; u < 8; ++u) a[u] = b2f(bias[fg * 8 + u]);
    for (int j = 0; j < 12; ++j) {
      float c = An[i * 12 + j];
      if (c != 0.0f) {
        u16x8 y = *(const u16x8*)(X + (s * 12 + j) * 256 + fg * 8);
#pragma unroll
        for (int u = 0; u < 8; ++u) a[u] += c * b2f(y[u]);
      }
    }
    u16x8 o;
#pragma unroll
    for (int u = 0; u < 8; ++u) {
      float vv = relu ? fmaxf(a[u], 0.0f) : a[u];
      o[u] = f2b(vv);
    }
    *(u16x8*)(out + base + idx * 8) = o;
  }
}

// ---------------- MFMA GEMM core: C[96,256] = A[96,K](lda) * Bt[256,K]^T -----
__device__ __forceinline__ void gemm_core(const void* __restrict__ A, int lda,
                                          int isf32,
                                          const u16* __restrict__ Bt,
                                          u16* As, u16* Bs,
                                          long m0, long n0, int K,
                                          f32x4 acc[6][4]) {
  const int tid = threadIdx.x;
  const int wave = tid >> 6, lane = tid & 63;
  const int q = lane >> 4, r16 = lane & 15;
  f32x4 zero = {0.f, 0.f, 0.f, 0.f};
#pragma unroll
  for (int a = 0; a < 6; ++a)
#pragma unroll
    for (int b = 0; b < 4; ++b) acc[a][b] = zero;

  for (int k0 = 0; k0 < K; k0 += 64) {
    if (isf32) {
      const float* Af = (const float*)A;
#pragma unroll
      for (int i = 0; i < 3; ++i) {
        int idx = i * 256 + tid;
        int rr = idx >> 3, cg = idx & 7;
        const float* sp = Af + (m0 + rr) * (long)lda + k0 + cg * 8;
        u16x8 t;
#pragma unroll
        for (int u = 0; u < 8; ++u) t[u] = f2b(sp[u]);
        *(u16x8*)(As + rr * 72 + cg * 8) = t;
      }
    } else {
      const u16* Ab = (const u16*)A;
#pragma unroll
      for (int i = 0; i < 3; ++i) {
        int idx = i * 256 + tid;
        int rr = idx >> 3, cg = idx & 7;
        *(u16x8*)(As + rr * 72 + cg * 8) =
            *(const u16x8*)(Ab + (m0 + rr) * (long)lda + k0 + cg * 8);
      }
    }
#pragma unroll
    for (int i = 0; i < 8; ++i) {
      int idx = i * 256 + tid;
      int rr = idx >> 3, cg = idx & 7;
      *(u16x8*)(Bs + rr * 72 + cg * 8) =
          *(const u16x8*)(Bt + (n0 + rr) * (long)K + k0 + cg * 8);
    }
    __syncthreads();
#pragma unroll
    for (int ks = 0; ks < 64; ks += 32) {
      bf16x8 af[6], bfv[4];
#pragma unroll
      for (int rb = 0; rb < 6; ++rb)
        af[rb] = *(const bf16x8*)(As + (rb * 16 + r16) * 72 + ks + q * 8);
#pragma unroll
      for (int cb = 0; cb < 4; ++cb)
        bfv[cb] = *(const bf16x8*)(Bs + ((wave * 4 + cb) * 16 + r16) * 72 + ks + q * 8);
#pragma unroll
      for (int rb = 0; rb < 6; ++rb)
#pragma unroll
        for (int cb = 0; cb < 4; ++cb)
          acc[rb][cb] = __builtin_amdgcn_mfma_f32_16x16x32_bf16(
              af[rb], bfv[cb], acc[rb][cb], 0, 0, 0);
    }
    __syncthreads();
  }
}

// ---------------- generic GEMM (+optional bias), bf16 out --------------------
// In-place safe when C rows alias A rows of the same block's slab.
template <bool BIAS>
__global__ void __launch_bounds__(256) k_gemm(const void* __restrict__ A, int lda,
                                              const u16* __restrict__ Bt,
                                              const u16* __restrict__ bias,
                                              u16* __restrict__ C,
                                              int K, int Ntot,
                                              const int* aflag) {
  __shared__ u16 As[96 * 72];
  __shared__ u16 Bs[256 * 72];
  f32x4 acc[6][4];
  const long m0 = (long)blockIdx.x * 96;
  const long n0 = (long)blockIdx.y * 256;
  int isf32 = aflag ? *aflag : 0;
  gemm_core(A, lda, isf32, Bt, As, Bs, m0, n0, K, acc);
  const int tid = threadIdx.x;
  const int wave = tid >> 6, lane = tid & 63;
  const int q = lane >> 4, r16 = lane & 15;
#pragma unroll
  for (int cb = 0; cb < 4; ++cb) {
    long col = n0 + (wave * 4 + cb) * 16 + r16;
    float bvv = BIAS ? b2f(bias[col]) : 0.0f;
#pragma unroll
    for (int rb = 0; rb < 6; ++rb) {
#pragma unroll
      for (int rr = 0; rr < 4; ++rr) {
        long row = m0 + rb * 16 + q * 4 + rr;
        C[row * (long)Ntot + col] = f2b(acc[rb][cb][rr] + bvv);
      }
    }
  }
}

// ---------------- attention: one block per sample, in-place into Q slots -----
__global__ void __launch_bounds__(256) k_attn(u16* __restrict__ QKV) {
  __shared__ u16 T[12 * 768];
  __shared__ float Sc[4][12][12];
  const int tid = threadIdx.x;
  const long base = (long)blockIdx.x * (12 * 768);
#pragma unroll
  for (int i = 0; i < 9; ++i) {
    int idx = i * 256 + tid;
    *(u16x4*)(T + idx * 4) = *(const u16x4*)(QKV + base + idx * 4);
  }
  __syncthreads();
  for (int p = tid; p < 576; p += 256) {
    int h = p / 144, r = p % 144, i = r / 12, j = r % 12;
    const u16* qp = T + i * 768 + h * 64;
    const u16* kp = T + j * 768 + 256 + h * 64;
    float s = 0.f;
#pragma unroll
    for (int dv = 0; dv < 8; ++dv) {
      u16x8 qv = *(const u16x8*)(qp + dv * 8);
      u16x8 kv = *(const u16x8*)(kp + dv * 8);
#pragma unroll
      for (int u = 0; u < 8; ++u) s += b2f(qv[u]) * b2f(kv[u]);
    }
    Sc[h][i][j] = s * 0.125f;
  }
  __syncthreads();
  if (tid < 48) {
    int h = tid / 12, i = tid % 12;
    float m = -1e30f;
#pragma unroll
    for (int j = 0; j < 12; ++j) m = fmaxf(m, Sc[h][i][j]);
    float e[12];
    float ssum = 0.f;
#pragma unroll
    for (int j = 0; j < 12; ++j) {
      e[j] = __expf(Sc[h][i][j] - m);
      ssum += e[j];
    }
    float inv = 1.0f / ssum;
#pragma unroll
    for (int j = 0; j < 12; ++j) Sc[h][i][j] = e[j] * inv;
  }
  __syncthreads();
  {
    int h = tid >> 6;
    int d = tid & 63;
    float vv[12];
#pragma unroll
    for (int j = 0; j < 12; ++j) vv[j] = b2f(T[j * 768 + 512 + h * 64 + d]);
#pragma unroll
    for (int i = 0; i < 12; ++i) {
      float o = 0.f;
#pragma unroll
      for (int j = 0; j < 12; ++j) o += Sc[h][i][j] * vv[j];
      QKV[base + i * 768 + h * 64 + d] = f2b(o);
    }
  }
}

// --------- residual + layernorm + lead-mix: one block per sample -------------
// Oa has row stride 768 (K-slot region of QKV). In-place safe for H.
__global__ void __launch_bounds__(256) k_resid_ln_mix(
    const u16* __restrict__ H, const u16* __restrict__ Oa,
    const u16* __restrict__ g, const u16* __restrict__ bb,
    u16* __restrict__ out) {
  __shared__ float Xn[12 * 256];
  __shared__ float An[144];
  __shared__ float mu[12], rs[12];
  build_anorm(An);
  const int tid = threadIdx.x;
  const long baseH = (long)blockIdx.x * 3072;
  const long baseO = (long)blockIdx.x * 9216;
#pragma unroll
  for (int i = 0; i < 3; ++i) {
    int idx = i * 256 + tid;        // 768 vec4 groups
    int row = idx >> 6, c4 = idx & 63;
    u16x4 hv = *(const u16x4*)(H + baseH + idx * 4);
    u16x4 ov = *(const u16x4*)(Oa + baseO + row * 768 + c4 * 4);
#pragma unroll
    for (int u = 0; u < 4; ++u) Xn[idx * 4 + u] = b2f(hv[u]) + b2f(ov[u]);
  }
  __syncthreads();
  {
    int wave = tid >> 6, lane = tid & 63;
    for (int rr = wave; rr < 12; rr += 4) {
      float s = 0.f, s2 = 0.f;
#pragma unroll
      for (int u = 0; u < 4; ++u) {
        float xv = Xn[rr * 256 + u * 64 + lane];
        s += xv;
        s2 += xv * xv;
      }
#pragma unroll
      for (int off = 32; off > 0; off >>= 1) {
        s += __shfl_down(s, off, 64);
        s2 += __shfl_down(s2, off, 64);
      }
      if (lane == 0) {
        float m = s * (1.0f / 256.0f);
        float var = s2 * (1.0f / 256.0f) - m * m;
        mu[rr] = m;
        rs[rr] = rsqrtf(var + 1e-5f);
      }
    }
  }
  __syncthreads();
  {
    float gv = b2f(g[tid]);
    float bv = b2f(bb[tid]);
    float xn[12];
#pragma unroll
    for (int i = 0; i < 12; ++i) {
      float x = Xn[i * 256 + tid];
      xn[i] = (x - mu[i]) * rs[i] * gv + bv;
    }
#pragma unroll
    for (int i = 0; i < 12; ++i) {
      float o = 0.f;
#pragma unroll
      for (int j = 0; j < 12; ++j) o += An[i * 12 + j] * xn[j];
      out[baseH + i * 256 + tid] = f2b(o);
    }
  }
}

// ------- fused QKV + attention + out-proj + residual + LN + lead-mix ---------
// FALLBACK path (small ws). 2 samples per block.
__global__ void __launch_bounds__(256) k_attn_mega(
    u16* __restrict__ H, const u16* __restrict__ inw,
    const u16* __restrict__ inb, const u16* __restrict__ outw,
    const u16* __restrict__ outb, const u16* __restrict__ lng,
    const u16* __restrict__ lnb) {
  __shared__ u16 Hs[32 * 264];
  __shared__ u16 Qs[32 * 264];
  __shared__ u16 KVs[24 * 512];
  __shared__ float Sc[4][2][12][12];
  __shared__ float An[144];
  __shared__ float mu[24], rs[24];
  const int tid = threadIdx.x;
  const int wave = tid >> 6, lane = tid & 63;
  const int q = lane >> 4, r16 = lane & 15;
  build_anorm(An);
  const long base = (long)blockIdx.x * 6144;
#pragma unroll
  for (int i = 0; i < 3; ++i) {
    int idx = i * 256 + tid;
    int rr = idx >> 5, cg = idx & 31;
    *(u16x8*)(Hs + rr * 264 + cg * 8) = *(const u16x8*)(H + base + idx * 8);
  }
  {
    int rr = 24 + (tid >> 5), cg = tid & 31;
    u16x8 z = {0, 0, 0, 0, 0, 0, 0, 0};
    *(u16x8*)(Hs + rr * 264 + cg * 8) = z;
  }
  __syncthreads();
  {
    f32x4 acc[2][12];
    f32x4 zero = {0.f, 0.f, 0.f, 0.f};
#pragma unroll
    for (int rb = 0; rb < 2; ++rb)
#pragma unroll
      for (int c = 0; c < 12; ++c) acc[rb][c] = zero;
    for (int k0 = 0; k0 < 256; k0 += 32) {
      bf16x8 af[2];
#pragma unroll
      for (int rb = 0; rb < 2; ++rb)
        af[rb] = *(const bf16x8*)(Hs + (rb * 16 + r16) * 264 + k0 + q * 8);
#pragma unroll
      for (int c = 0; c < 12; ++c) {
        bf16x8 bf = *(const bf16x8*)(inw + (long)((wave * 12 + c) * 16 + r16) * 256 + k0 + q * 8);
#pragma unroll
        for (int rb = 0; rb < 2; ++rb)
          acc[rb][c] = __builtin_amdgcn_mfma_f32_16x16x32_bf16(af[rb], bf, acc[rb][c], 0, 0, 0);
      }
    }
#pragma unroll
    for (int c = 0; c < 12; ++c) {
      int col = (wave * 12 + c) * 16 + r16;
      float bv = b2f(inb[col]);
#pragma unroll
      for (int rb = 0; rb < 2; ++rb)
#pragma unroll
        for (int rr2 = 0; rr2 < 4; ++rr2) {
          int row = rb * 16 + q * 4 + rr2;
          float v = acc[rb][c][rr2] + bv;
          if (col < 256) Qs[row * 264 + col] = f2b(v);
          else if (row < 24) KVs[row * 512 + col - 256] = f2b(v);
        }
    }
  }
  __syncthreads();
  {
    int h = wave;
#pragma unroll
    for (int t = 0; t < 5; ++t) {
      int p = t * 64 + lane;
      if (p < 288) {
        int s = p / 144, r = p - s * 144, i = r / 12, j = r - i * 12;
        const u16* qp = Qs + (s * 12 + i) * 264 + h * 64;
        const u16* kp = KVs + (s * 12 + j) * 512 + h * 64;
        float dot = 0.f;
#pragma unroll
        for (int dv = 0; dv < 8; ++dv) {
          u16x8 qv = *(const u16x8*)(qp + dv * 8);
          u16x8 kv = *(const u16x8*)(kp + dv * 8);
#pragma unroll
          for (int u = 0; u < 8; ++u) dot += b2f(qv[u]) * b2f(kv[u]);
        }
        Sc[h][s][i][j] = dot * 0.125f;
      }
    }
  }
  __syncthreads();
  if (lane < 24) {
    int h = wave, s = lane / 12, i = lane - (lane / 12) * 12;
    float m = -1e30f;
#pragma unroll
    for (int j = 0; j < 12; ++j) m = fmaxf(m, Sc[h][s][i][j]);
    float e[12];
    float ssum = 0.f;
#pragma unroll
    for (int j = 0; j < 12; ++j) {
      e[j] = __expf(Sc[h][s][i][j] - m);
      ssum += e[j];
    }
    float inv = 1.0f / ssum;
#pragma unroll
    for (int j = 0; j < 12; ++j) Sc[h][s][i][j] = e[j] * inv;
  }
  __syncthreads();
  {
    int h = wave, d = lane;
    for (int si = 0; si < 24; ++si) {
      int s = si / 12;
      float o = 0.f;
#pragma unroll
      for (int j = 0; j < 12; ++j)
        o += Sc[h][s][si - s * 12][j] * b2f(KVs[(s * 12 + j) * 512 + 256 + h * 64 + d]);
      Qs[si * 264 + h * 64 + d] = f2b(o);
    }
  }
  __syncthreads();
  {
    f32x4 acc[2][4];
    f32x4 zero = {0.f, 0.f, 0.f, 0.f};
#pragma unroll
    for (int rb = 0; rb < 2; ++rb)
#pragma unroll
      for (int cb = 0; cb < 4; ++cb) acc[rb][cb] = zero;
    for (int k0 = 0; k0 < 256; k0 += 32) {
      bf16x8 af[2];
#pragma unroll
      for (int rb = 0; rb < 2; ++rb)
        af[rb] = *(const bf16x8*)(Qs + (rb * 16 + r16) * 264 + k0 + q * 8);
#pragma unroll
      for (int cb = 0; cb < 4; ++cb) {
        bf16x8 bf = *(const bf16x8*)(outw + (long)((wave * 4 + cb) * 16 + r16) * 256 + k0 + q * 8);
#pragma unroll
        for (int rb = 0; rb < 2; ++rb)
          acc[rb][cb] = __builtin_amdgcn_mfma_f32_16x16x32_bf16(af[rb], bf, acc[rb][cb], 0, 0, 0);
      }
    }
#pragma unroll
    for (int cb = 0; cb < 4; ++cb) {
      int col = (wave * 4 + cb) * 16 + r16;
      float ob = b2f(outb[col]);
#pragma unroll
      for (int rb = 0; rb < 2; ++rb)
#pragma unroll
        for (int rr2 = 0; rr2 < 4; ++rr2) {
          int row = rb * 16 + q * 4 + rr2;
          if (row < 24) {
            float x = acc[rb][cb][rr2] + ob + b2f(Hs[row * 264 + col]);
            Hs[row * 264 + col] = f2b(x);
          }
        }
    }
  }
  __syncthreads();
  {
    for (int rr2 = wave * 6; rr2 < wave * 6 + 6; ++rr2) {
      float s1 = 0.f, s2 = 0.f;
#pragma unroll
      for (int u = 0; u < 4; ++u) {
        float xv = b2f(Hs[rr2 * 264 + u * 64 + lane]);
        s1 += xv;
        s2 += xv * xv;
      }
#pragma unroll
      for (int off = 32; off > 0; off >>= 1) {
        s1 += __shfl_down(s1, off, 64);
        s2 += __shfl_down(s2, off, 64);
      }
      if (lane == 0) {
        float m = s1 * (1.0f / 256.0f);
        mu[rr2] = m;
        rs[rr2] = rsqrtf(s2 * (1.0f / 256.0f) - m * m + 1e-5f);
      }
    }
  }
  __syncthreads();
  {
    float gvv = b2f(lng[tid]);
    float bvv = b2f(lnb[tid]);
#pragma unroll
    for (int s = 0; s < 2; ++s) {
      float xn[12];
#pragma unroll
      for (int j = 0; j < 12; ++j) {
        int row = s * 12 + j;
        xn[j] = (b2f(Hs[row * 264 + tid]) - mu[row]) * rs[row] * gvv + bvv;
      }
#pragma unroll
      for (int i = 0; i < 12; ++i) {
        float o = 0.f;
#pragma unroll
        for (int j = 0; j < 12; ++j) o += An[i * 12 + j] * xn[j];
        H[base + (s * 12 + i) * 256 + tid] = f2b(o);
      }
    }
  }
}

// ---------- final GEMM + bias + attention-pooling; OUTPUT = float32 ----------
__global__ void __launch_bounds__(256) k_gemm_pool(const u16* __restrict__ A,
                                                   const u16* __restrict__ Bt,
                                                   const u16* __restrict__ bias,
                                                   float* __restrict__ out) {
  __shared__ __align__(16) char smraw[50688];
  __shared__ float rowsum[96];
  __shared__ float wsm[96];
  u16* As = (u16*)smraw;
  u16* Bs = As + 96 * 72;
  u16* Y = (u16*)smraw;
  f32x4 acc[6][4];
  const long m0 = (long)blockIdx.x * 96;
  gemm_core(A, 256, 0, Bt, As, Bs, m0, 0, 256, acc);
  const int tid = threadIdx.x;
  const int wave = tid >> 6, lane = tid & 63;
  const int q = lane >> 4, r16 = lane & 15;
#pragma unroll
  for (int cb = 0; cb < 4; ++cb) {
    int col = (wave * 4 + cb) * 16 + r16;
    float bvv = b2f(bias[col]);
#pragma unroll
    for (int rb = 0; rb < 6; ++rb)
#pragma unroll
      for (int rr = 0; rr < 4; ++rr) {
        int row = rb * 16 + q * 4 + rr;
        Y[row * 264 + col] = f2b(acc[rb][cb][rr] + bvv);
      }
  }
  __syncthreads();
  for (int row = wave; row < 96; row += 4) {
    float s = 0.f;
#pragma unroll
    for (int u = 0; u < 4; ++u) s += b2f(Y[row * 264 + u * 64 + lane]);
#pragma unroll
    for (int off = 32; off > 0; off >>= 1) s += __shfl_down(s, off, 64);
    if (lane == 0) rowsum[row] = s;
  }
  __syncthreads();
  if (tid < 8) {
    float m = -1e30f;
#pragma unroll
    for (int l = 0; l < 12; ++l) m = fmaxf(m, rowsum[tid * 12 + l]);
    float e[12];
    float ssum = 0.f;
#pragma unroll
    for (int l = 0; l < 12; ++l) {
      e[l] = __expf((rowsum[tid * 12 + l] - m) * (1.0f / 256.0f));
      ssum += e[l];
    }
    float inv = 1.0f / ssum;
#pragma unroll
    for (int l = 0; l < 12; ++l) wsm[tid * 12 + l] = e[l] * inv;
  }
  __syncthreads();
  {
    int s = tid >> 5, cg = tid & 31;
    float wa[8], mx[8];
#pragma unroll
    for (int u = 0; u < 8; ++u) {
      wa[u] = 0.f;
      mx[u] = -1e30f;
    }
#pragma unroll
    for (int l = 0; l < 12; ++l) {
      float w = wsm[s * 12 + l];
      u16x8 yv = *(const u16x8*)(Y + (s * 12 + l) * 264 + cg * 8);
#pragma unroll
      for (int u = 0; u < 8; ++u) {
        float y = b2f(yv[u]);
        wa[u] += w * y;
        mx[u] = fmaxf(mx[u], y);
      }
    }
    long ob = ((long)blockIdx.x * 8 + s) * 512;
#pragma unroll
    for (int u = 0; u < 8; ++u) {
      out[ob + cg * 8 + u] = wa[u];
      out[ob + 256 + cg * 8 + u] = mx[u];
    }
  }
}

extern "C" void kernel_launch(void* const* d_in, const int* in_sizes, int n_in,
                              void* d_out, int out_size, void* d_ws,
                              size_t ws_size, hipStream_t stream) {
  (void)in_sizes; (void)n_in; (void)out_size;
  const void* x    = d_in[0];
  const void* W1   = d_in[1];
  const void* b1   = d_in[2];
  const void* W2   = d_in[3];
  const void* b2   = d_in[4];
  const void* W3   = d_in[5];
  const void* b3   = d_in[6];
  const void* inw  = d_in[7];
  const void* inb  = d_in[8];
  const void* outw = d_in[9];
  const void* outb = d_in[10];
  const void* lng  = d_in[11];
  const void* lnb  = d_in[12];
  float* out = (float*)d_out;

  u16* ws16 = (u16*)d_ws;
  int* flagX = (int*)d_ws;
  int* flagW = (int*)d_ws + 1;
  u16* W1T    = ws16 + 64;
  u16* W2T    = W1T + 131072;
  u16* W3T    = W2T + 65536;
  u16* inw_b  = W3T + 65536;
  u16* outw_b = inw_b + 196608;
  u16* b1b    = outw_b + 65536;
  u16* b2b    = b1b + 256;
  u16* b3b    = b2b + 256;
  u16* inbb   = b3b + 256;
  u16* outbb  = inbb + 768;
  u16* lngb   = outbb + 256;
  u16* lnbb   = lngb + 256;
  u16* BUF    = lnbb + 256;            // 25165824 elems (H)
  u16* QKV    = BUF + 25165824L;       // 75497472 elems (pipeline A only)
  const size_t NEED_A = (size_t)(QKV + 75497472L - ws16) * 2;  // ~202.4 MB

  k_detect<<<1, 256, 0, stream>>>(x, flagX);
  k_detect<<<1, 256, 0, stream>>>(W1, flagW);

  k_cvt<<<1, 256, 0, stream>>>(b1, b1b, 256, flagW);
  k_cvt<<<1, 256, 0, stream>>>(b2, b2b, 256, flagW);
  k_cvt<<<1, 256, 0, stream>>>(b3, b3b, 256, flagW);
  k_cvt<<<3, 256, 0, stream>>>(inb, inbb, 768, flagW);
  k_cvt<<<1, 256, 0, stream>>>(outb, outbb, 256, flagW);
  k_cvt<<<1, 256, 0, stream>>>(lng, lngb, 256, flagW);
  k_cvt<<<1, 256, 0, stream>>>(lnb, lnbb, 256, flagW);
  k_cvt<<<768, 256, 0, stream>>>(inw, inw_b, 196608, flagW);
  k_cvt<<<256, 256, 0, stream>>>(outw, outw_b, 65536, flagW);
  k_transpose_cvt<<<512, 256, 0, stream>>>(W1, W1T, 512, 256, flagW);
  k_transpose_cvt<<<256, 256, 0, stream>>>(W2, W2T, 256, 256, flagW);
  k_transpose_cvt<<<256, 256, 0, stream>>>(W3, W3T, 256, 256, flagW);

  // G1 = x@W1 ; H1 = relu(A.G1+b1) ; G2 = H1@W2 ; H2 = relu(A.G2+b2)
  k_gemm<false><<<dim3(1024, 1), 256, 0, stream>>>(x, 512, W1T, nullptr, BUF, 512, 256, flagX);
  k_mix<<<4096, 256, 0, stream>>>(BUF, b1b, BUF, 1);
  k_gemm<false><<<dim3(1024, 1), 256, 0, stream>>>(BUF, 256, W2T, nullptr, BUF, 256, 256, nullptr);
  k_mix<<<4096, 256, 0, stream>>>(BUF, b2b, BUF, 1);

  if (ws_size >= NEED_A) {
    // Pipeline A: un-fused attention block via efficient GEMM slabs.
    // QKV = H2 @ in_w^T + in_b
    k_gemm<true><<<dim3(1024, 3), 256, 0, stream>>>(BUF, 256, inw_b, inbb, QKV, 256, 768, nullptr);
    // attention, O -> Q slots (in place, per-block LDS-buffered)
    k_attn<<<8192, 256, 0, stream>>>(QKV);
    // O2 = O @ out_w^T + out_b -> K slots of QKV (disjoint from Q-slot reads)
    k_gemm<true><<<dim3(1024, 1), 256, 0, stream>>>(QKV, 768, outw_b, outbb, QKV + 256, 256, 768, nullptr);
    // HL = A.( LN(H2 + O2) ), in place into BUF
    k_resid_ln_mix<<<8192, 256, 0, stream>>>(BUF, QKV + 256, lngb, lnbb, BUF);
  } else {
    // Fallback: fused mega-kernel (passing, but latency-bound).
    k_attn_mega<<<4096, 256, 0, stream>>>(BUF, inw_b, inbb, outw_b, outbb, lngb, lnbb);
  }
  // out = pool( HL@W3 + b3 )  -- float32 output
  k_gemm_pool<<<1024, 256, 0, stream>>>(BUF, W3T, b3b, out);
}